// Round 9
// baseline (137.393 us; speedup 1.0000x reference)
//
#include <hip/hip_runtime.h>
#include <math.h>

// Problem constants (B,C,H,W = 8,256,64,64; N = H*W = 4096)
#define BQ 8
#define CQ 256
#define NQ 4096
#define MT 64             // m-tile per block -> 512 blocks, 2/CU
#define NCH 128           // chunks of 32n

typedef short s16x8 __attribute__((ext_vector_type(8)));
typedef short s16x4 __attribute__((ext_vector_type(4)));
typedef float f32x4 __attribute__((ext_vector_type(4)));
typedef unsigned int uint;

static __device__ __forceinline__ float4 ld4(const float* p) { return *(const float4*)p; }

static constexpr float LOG2E = 1.4426950408889634f;

static __device__ __forceinline__ short f2bf(float f) {
    return __builtin_bit_cast(short, (__bf16)f);
}
// monotonic uint key for float compare via atomicMax/Min
static __device__ __forceinline__ uint fkey(float f) {
    uint b = __builtin_bit_cast(uint, f);
    return b ^ (0x80000000u | (uint)((int)b >> 31));
}
static __device__ __forceinline__ float fdec(uint u) {
    uint b = (u & 0x80000000u) ? (u ^ 0x80000000u) : ~u;
    return __builtin_bit_cast(float, b);
}

// -------- K1: f' = (wq.x)*log2e, g = wk.x, xbf = bf16(x), fused batch max/min --------
__global__ void k_fg(const float* __restrict__ x, const float* __restrict__ wq,
                     const float* __restrict__ wk, float* __restrict__ fs,
                     float* __restrict__ g, short* __restrict__ xbf,
                     uint* __restrict__ fmxu, uint* __restrict__ fmnu) {
    int b = blockIdx.y;
    int t = threadIdx.x;
    int nl = (t & 31) * 2;
    int cg = t >> 5;                     // 0..7
    int n = blockIdx.x * 64 + nl;
    const float* xb = x + (size_t)b * CQ * NQ + n;
    uint* xo = (uint*)(xbf + (size_t)b * CQ * NQ + n);
    float f0 = 0.f, f1 = 0.f, g0 = 0.f, g1 = 0.f;
    int c0 = cg * 32;
#pragma unroll 8
    for (int c = c0; c < c0 + 32; ++c) {
        float2 v = *(const float2*)&xb[(size_t)c * NQ];
        f0 = fmaf(wq[c], v.x, f0);
        f1 = fmaf(wq[c], v.y, f1);
        g0 = fmaf(wk[c], v.x, g0);
        g1 = fmaf(wk[c], v.y, g1);
        uint p = (uint)(unsigned short)f2bf(v.x) | ((uint)(unsigned short)f2bf(v.y) << 16);
        xo[c * (NQ / 2)] = p;
    }
    __shared__ float sf[8][64], sg2[8][64];
    sf[cg][nl] = f0;  sf[cg][nl + 1] = f1;
    sg2[cg][nl] = g0; sg2[cg][nl + 1] = g1;
    __syncthreads();
    if (t < 64) {
        float f = 0.f, gg = 0.f;
#pragma unroll
        for (int i = 0; i < 8; ++i) { f += sf[i][t]; gg += sg2[i][t]; }
        f *= LOG2E;
        fs[b * NQ + blockIdx.x * 64 + t] = f;
        g[b * NQ + blockIdx.x * 64 + t]  = gg;
        float mx = f, mn = f;
#pragma unroll
        for (int off = 32; off; off >>= 1) {
            mx = fmaxf(mx, __shfl_xor(mx, off));
            mn = fminf(mn, __shfl_xor(mn, off));
        }
        if (t == 0) {
            atomicMax(&fmxu[b], fkey(mx));
            atomicMin(&fmnu[b], fkey(mn));
        }
    }
}

// LDS map (bytes):
//   [0, 32768)      : ring, 2 x 16KB slots ([256c][64B] = 256c x 32n bf16, linear)
//                     post-loop overlay: y_lds (64m x 512B rows, XOR-swizzled)
//   [32768, 43008)  : e dbuf, 2 x 5120B ([64m][80B] rows: 32n bf16 + 16B pad)
//   [43008, 44032)  : zbuf (4 producers x 64m f32)
#define EOFF 32768
#define ESLOT 5120
#define ZOFF 43008
#define SMEM_BYTES 44032

// stage one 16KB chunk (256c x 32n) linearly; all 512 threads, 2 issues each
#define STAGE(slot, ch)                                                            \
    {                                                                              \
        _Pragma("unroll")                                                          \
        for (int i_ = 0; i_ < 2; ++i_) {                                           \
            int off_ = tid * 16 + i_ * 8192;                                       \
            int row_ = off_ >> 6, nb_ = off_ & 63;                                 \
            const short* src_ = xb + (size_t)row_ * NQ + (ch) * 32 + (nb_ >> 1);   \
            __builtin_amdgcn_global_load_lds(                                      \
                (const __attribute__((address_space(1))) void*)src_,               \
                (__attribute__((address_space(3))) void*)(smem + (slot) * 16384 + off_), \
                16, 0, 0);                                                         \
        }                                                                          \
    }

// -------- K2 fused, producer/consumer: y[c][m] = sum_n x[c][n] e[n,m];
//          o = (1-gam)*wv*(y/Z) + gam*x
// 512 blocks (2/CU) x 512 thr (8 waves).
// Waves 0..3 = CONSUMERS: wc = w>>1 (c-half), wm = w&1 (m-half); wave tile
//   128c x 32m (jc=8 x jm=2); pure ds_read + MFMA, no exps.
// Waves 4..7 = PRODUCERS: p = w-4 owns n-slot p (8n) x 64m (lane = m);
//   computes e=exp2(f*g-M) one chunk ahead into e dbuf; Z is lane-local.
__global__ void __launch_bounds__(512, 4) k_attn(
    const short* __restrict__ xbf, const float* __restrict__ fsp,
    const float* __restrict__ gp, const uint* __restrict__ fmxu,
    const uint* __restrict__ fmnu, const float* __restrict__ wv,
    const float* __restrict__ x, const float* __restrict__ gamma,
    float* __restrict__ out) {
    __shared__ __align__(16) char smem[SMEM_BYTES];

    int bid = blockIdx.x;
    int b = bid & 7;            // batch -> XCD affinity (2MB xbf slice per XCD L2)
    int mblk = bid >> 3;        // 0..63
    int m0 = mblk * MT;
    int tid = threadIdx.x;
    int l = tid & 63;
    int w = tid >> 6;           // 0..7
    int q = l >> 4;             // k-slot
    int cr = l & 15;            // A-row / B-col within frag

    const short* xb = xbf + (size_t)b * CQ * NQ;
    const float* fb = fsp + b * NQ;

    // ---- prolog: stage chunk 0 ----
    STAGE(0, 0)

    // consumer state
    int wc = w >> 1;            // c-half (consumers)
    int wm = w & 1;             // m-half (consumers)
    f32x4 acc[8][2];
#pragma unroll
    for (int jc = 0; jc < 8; ++jc)
#pragma unroll
        for (int jm = 0; jm < 2; ++jm) acc[jc][jm] = (f32x4){0.f, 0.f, 0.f, 0.f};

    // producer state
    int p = w - 4;
    float gv = 0.f, nM = 0.f, zac = 0.f;
    float4 fca = {0,0,0,0}, fcb = {0,0,0,0}, fna = {0,0,0,0}, fnb = {0,0,0,0};

    if (w >= 4) {
        float fmx = fdec(fmxu[b]), fmn = fdec(fmnu[b]);
        gv = gp[b * NQ + m0 + l];
        nM = -((gv >= 0.f) ? gv * fmx : gv * fmn);
        // e(0): direct f load, compute, write e dbuf slot 0
        float4 a0 = ld4(fb + p * 8);
        float4 b0 = ld4(fb + p * 8 + 4);
        float fq[8] = {a0.x, a0.y, a0.z, a0.w, b0.x, b0.y, b0.z, b0.w};
        s16x8 ev;
#pragma unroll
        for (int i = 0; i < 8; ++i) {
            float e = __builtin_amdgcn_exp2f(fmaf(fq[i], gv, nM));
            zac += e;
            ev[i] = f2bf(e);
        }
        *(s16x8*)(smem + EOFF + l * 80 + p * 16) = ev;
        // prefetch f for chunks 1 and 2
        fca = ld4(fb + 32 + p * 8);  fcb = ld4(fb + 32 + p * 8 + 4);
        fna = ld4(fb + 64 + p * 8);  fnb = ld4(fb + 64 + p * 8 + 4);
    }
    __syncthreads();   // ring(0) + e(0) ready

    for (int s = 0; s < NCH; ++s) {
        if (s + 1 < NCH) STAGE((s + 1) & 1, s + 1)   // lands before end barrier
        if (w < 4) {
            // ---- consumer: 2 B-frags from e dbuf, 8 A-frags from ring, 16 MFMA ----
            const char* cbuf = smem + (s & 1) * 16384;
            const char* ebuf = smem + EOFF + (s & 1) * ESLOT;
            s16x8 bv0 = *(const s16x8*)(ebuf + (wm * 32 + cr) * 80 + q * 16);
            s16x8 bv1 = *(const s16x8*)(ebuf + (wm * 32 + 16 + cr) * 80 + q * 16);
#pragma unroll
            for (int jc = 0; jc < 8; ++jc) {
                s16x8 av = *(const s16x8*)(cbuf + (wc * 128 + jc * 16 + cr) * 64 + q * 16);
                acc[jc][0] = __builtin_amdgcn_mfma_f32_16x16x32_bf16(av, bv0, acc[jc][0], 0, 0, 0);
                acc[jc][1] = __builtin_amdgcn_mfma_f32_16x16x32_bf16(av, bv1, acc[jc][1], 0, 0, 0);
            }
        } else if (s + 1 < NCH) {
            // ---- producer: e(s+1) into dbuf slot (s+1)&1, rotate f prefetch ----
            float fq[8] = {fca.x, fca.y, fca.z, fca.w, fcb.x, fcb.y, fcb.z, fcb.w};
            s16x8 ev;
#pragma unroll
            for (int i = 0; i < 8; ++i) {
                float e = __builtin_amdgcn_exp2f(fmaf(fq[i], gv, nM));
                zac += e;
                ev[i] = f2bf(e);
            }
            *(s16x8*)(smem + EOFF + ((s + 1) & 1) * ESLOT + l * 80 + p * 16) = ev;
            fca = fna; fcb = fnb;
            int ch = (s + 3) & (NCH - 1);
            fna = ld4(fb + ch * 32 + p * 8);
            fnb = ld4(fb + ch * 32 + p * 8 + 4);
        }
        __syncthreads();   // ring(s+1) + e(s+1) ready; slot s freed
    }

    // ---- Z: producers publish lane-local sums; consumers combine ----
    if (w >= 4) ((float*)(smem + ZOFF))[p * 64 + l] = zac;
    __syncthreads();

    // ---- y_norm -> LDS (consumers): y_lds[m][c] bf16, 512B rows, XOR-swizzled ----
    if (w < 4) {
        const float* zb = (const float*)(smem + ZOFF);
        float rzl[2];
#pragma unroll
        for (int jm = 0; jm < 2; ++jm) {
            int mloc = wm * 32 + jm * 16 + cr;
            float z = zb[mloc] + zb[64 + mloc] + zb[128 + mloc] + zb[192 + mloc];
            rzl[jm] = 1.0f / z;
        }
#pragma unroll
        for (int jc = 0; jc < 8; ++jc) {
#pragma unroll
            for (int jm = 0; jm < 2; ++jm) {
                int mloc = wm * 32 + jm * 16 + cr;
                int cb = (wc * 256 + jc * 32 + q * 8) ^ ((mloc & 7) << 4);
                s16x4 v;
#pragma unroll
                for (int r = 0; r < 4; ++r) v[r] = f2bf(acc[jc][jm][r] * rzl[jm]);
                *(s16x4*)(smem + mloc * 512 + cb) = v;
            }
        }
    }
    __syncthreads();

    // ---- GEMM2: o[c_out][m] = wv[c_out][:] . y_norm[:][m], K=256 (all 8 waves) ----
    int co0 = w * 32;
    f32x4 acc2[2][4];
#pragma unroll
    for (int j2 = 0; j2 < 2; ++j2)
#pragma unroll
        for (int jm2 = 0; jm2 < 4; ++jm2) acc2[j2][jm2] = (f32x4){0.f, 0.f, 0.f, 0.f};

#pragma unroll 2
    for (int ks = 0; ks < 8; ++ks) {
        s16x8 a2[2];
#pragma unroll
        for (int j2 = 0; j2 < 2; ++j2) {
            const float* wr = wv + (size_t)(co0 + j2 * 16 + cr) * CQ + ks * 32 + q * 8;
            float4 wa = ld4(wr);
            float4 wb = ld4(wr + 4);
            a2[j2][0] = f2bf(wa.x); a2[j2][1] = f2bf(wa.y);
            a2[j2][2] = f2bf(wa.z); a2[j2][3] = f2bf(wa.w);
            a2[j2][4] = f2bf(wb.x); a2[j2][5] = f2bf(wb.y);
            a2[j2][6] = f2bf(wb.z); a2[j2][7] = f2bf(wb.w);
        }
#pragma unroll
        for (int jm2 = 0; jm2 < 4; ++jm2) {
            int mloc = jm2 * 16 + cr;
            s16x8 b2 = *(const s16x8*)(smem + mloc * 512 + ((ks * 64 + q * 16) ^ ((mloc & 7) << 4)));
#pragma unroll
            for (int j2 = 0; j2 < 2; ++j2)
                acc2[j2][jm2] = __builtin_amdgcn_mfma_f32_16x16x32_bf16(a2[j2], b2, acc2[j2][jm2], 0, 0, 0);
        }
    }

    // ---- epilogue ----
    float gam = gamma[0];
    float omg = 1.f - gam;
    if (gam != 0.f) {
#pragma unroll
        for (int j2 = 0; j2 < 2; ++j2)
#pragma unroll
            for (int jm2 = 0; jm2 < 4; ++jm2)
#pragma unroll
                for (int r = 0; r < 4; ++r) {
                    int c_out = co0 + j2 * 16 + q * 4 + r;
                    size_t idx = ((size_t)b * CQ + c_out) * NQ + m0 + jm2 * 16 + cr;
                    __builtin_nontemporal_store(
                        fmaf(gam, x[idx], acc2[j2][jm2][r] * omg), out + idx);
                }
    } else {
#pragma unroll
        for (int j2 = 0; j2 < 2; ++j2)
#pragma unroll
            for (int jm2 = 0; jm2 < 4; ++jm2)
#pragma unroll
                for (int r = 0; r < 4; ++r) {
                    int c_out = co0 + j2 * 16 + q * 4 + r;
                    size_t idx = ((size_t)b * CQ + c_out) * NQ + m0 + jm2 * 16 + cr;
                    __builtin_nontemporal_store(acc2[j2][jm2][r] * omg, out + idx);
                }
    }
}

extern "C" void kernel_launch(void* const* d_in, const int* in_sizes, int n_in,
                              void* d_out, int out_size, void* d_ws, size_t ws_size,
                              hipStream_t stream) {
    const float* x     = (const float*)d_in[0];
    const float* wq    = (const float*)d_in[1];
    const float* wk    = (const float*)d_in[2];
    const float* wv    = (const float*)d_in[3];
    const float* gamma = (const float*)d_in[4];
    float* out = (float*)d_out;

    // ws (floats): fs[B*N] | g[B*N] | fmxu[8]+fmnu[8] (uint) | pad -> xbf (bf16) [B*C*N]
    float* ws  = (float*)d_ws;
    float* fs  = ws;
    float* g   = ws + BQ * NQ;
    uint* fmxu = (uint*)(ws + 2 * BQ * NQ);
    uint* fmnu = fmxu + 8;
    short* xbf = (short*)(ws + 2 * BQ * NQ + 64);

    hipMemsetAsync(fmxu, 0x00, 32, stream);   // lowest key
    hipMemsetAsync(fmnu, 0xFF, 32, stream);   // highest key
    hipLaunchKernelGGL(k_fg, dim3(NQ / 64, BQ), dim3(256), 0, stream,
                       x, wq, wk, fs, g, xbf, fmxu, fmnu);
    hipLaunchKernelGGL(k_attn, dim3(BQ * (NQ / MT)), dim3(512), 0, stream,
                       xbf, fs, g, fmxu, fmnu, wv, x, gamma, out);
}